// Round 16
// baseline (1392.637 us; speedup 1.0000x reference)
//
#include <hip/hip_runtime.h>
#include <stdint.h>
#include <math.h>

// BitNetAttention on MI355X (gfx950), round 15: gemm8 front-loaded fragment
// reads + counted lgkmcnt. R14 still serialized DS and MFMA via per-phase
// lgkmcnt(0). Now all 24 ds_read_b128 for tile T issue at tile start in 3
// sched_barrier(0)-pinned groups (12/4/8); phases wait lgkmcnt(12/8/0/-).
// Stage+vmcnt schedule byte-identical to R13 (readiness invariant: after
// ph4's vmcnt(4) the <=4 outstanding are always the newest ph3/ph4 stages,
// so tile T+1 is fully landed). Attn/epilogue/converts unchanged.

#define HDIM   4096
#define SEQ    2048
#define NBATCH 2
#define NROWS  (NBATCH * SEQ)   // 4096
#define NHEADS 32
#define DHEAD  128
#define QBLK   128

typedef __attribute__((ext_vector_type(8))) short short8;
typedef __attribute__((ext_vector_type(4))) short short4v;
typedef __attribute__((ext_vector_type(4))) float f32x4;
typedef unsigned short u16;
typedef unsigned int   u32;

__device__ __forceinline__ float bf2f(u16 u) {
  union { float f; u32 i; } x; x.i = ((u32)u) << 16; return x.f;
}
__device__ __forceinline__ u16 f2bf(float f) {
  union { float f; u32 i; } x; x.f = f;
  u32 r = x.i + 0x7FFFu + ((x.i >> 16) & 1u);   // RNE
  return (u16)(r >> 16);
}
__device__ __forceinline__ u16 f2bf_t(float f) {   // truncating (cheap)
  union { float f; u32 i; } x; x.f = f;
  return (u16)(x.i >> 16);
}
// bare hardware exp2 (1 instr; FTZ + exp2(-inf)=0 fine for softmax domain)
__device__ __forceinline__ float exp2v(float x) {
  float r; asm("v_exp_f32 %0, %1" : "=v"(r) : "v"(x)); return r;
}

__device__ __forceinline__ void gload16(const u16* g, u16* l) {
  __builtin_amdgcn_global_load_lds(
      (const __attribute__((address_space(1))) u32*)g,
      (__attribute__((address_space(3))) u32*)l, 16, 0, 0);
}

__device__ __forceinline__ void unpack2(u32 v, float& a, float& b) {
  a = bf2f((u16)(v & 0xffffu)); b = bf2f((u16)(v >> 16));
}
__device__ __forceinline__ u32 pack2(float a, float b) {
  return (u32)f2bf(a) | ((u32)f2bf(b) << 16);
}

// ---------------- fp32 -> bf16 convert (vectorized) ----------------
__global__ void f2bf_vec(const float* __restrict__ in, u16* __restrict__ out, int n4) {
  int i = blockIdx.x * blockDim.x + threadIdx.x;
  const int stride = gridDim.x * blockDim.x;
  for (; i < n4; i += stride) {
    float4 v = reinterpret_cast<const float4*>(in)[i];
    u32 lo = (u32)f2bf(v.x) | ((u32)f2bf(v.y) << 16);
    u32 hi = (u32)f2bf(v.z) | ((u32)f2bf(v.w) << 16);
    reinterpret_cast<uint2*>(out)[i] = make_uint2(lo, hi);
  }
}

// ---------------- RoPE tables [SEQ][64] fp32 ----------------
__global__ void rope_tables_k(float* __restrict__ cosT, float* __restrict__ sinT) {
  int idx = blockIdx.x * blockDim.x + threadIdx.x;
  if (idx >= SEQ * 64) return;
  int s = idx >> 6, d = idx & 63;
  float ex = (float)(2 * d) / 128.0f;
  float inv = powf(10000.0f, -ex);
  float f = (float)s * inv;
  cosT[idx] = cosf(f);
  sinT[idx] = sinf(f);
}

// ---------------- 8-phase GEMM: C[4096][4096] = (A * B^T) * scale ----------------
// OUTF: 0 = bf16 out, 1 = fp32 out, 2 = bf16 out + fused RoPE (Q/K GEMMs).
template<int OUTF>
__global__ __launch_bounds__(512, 2)
void gemm8(const u16* __restrict__ Am, const u16* __restrict__ Bm,
           void* __restrict__ Cout, const float* __restrict__ scale_ptr,
           const float* __restrict__ cosT, const float* __restrict__ sinT) {
  extern __shared__ __align__(16) u16 ldsp[];

  const int tid = threadIdx.x;
  const int w = tid >> 6, lane = tid & 63;
  const int llo = lane & 15, lhi = (lane >> 4) & 3;
  const int wr = w >> 2, wc = w & 3;           // 2 x 4 waves

  const int bid = blockIdx.x;
  const int xcd = bid & 7, ii = bid >> 3;
  const int by = (xcd >> 1) * 4 + (ii & 3);
  const int bx = (xcd & 1) * 8 + (ii >> 2);
  const int rowBase = by * 256, colBase = bx * 256;
  const float scl = scale_ptr[0];

  auto stage_half = [&](const u16* G, int obase, int ts, int h, int opB) {
    const int p = ts & 1;
    const u32 base = (opB ? 32768u : 0u) + (u32)p * 16384u + (u32)h * 8192u;
#pragma unroll
    for (int i = 0; i < 2; ++i) {
      const int ru = i * 64 + w * 8;
      const int r = ru + (lane >> 3);
      const int cc = (lane & 7) ^ (r & 7);
      gload16(G + (size_t)(obase + h * 128 + r) * HDIM + ts * 64 + cc * 8,
              ldsp + base + (u32)ru * 64u);
    }
  };

  f32x4 acc[8][4];
#pragma unroll
  for (int m = 0; m < 8; ++m)
#pragma unroll
    for (int n = 0; n < 4; ++n) acc[m][n] = (f32x4)0.0f;

  // all fragments of the current K-tile live in registers (front-loaded)
  short8 af0_[4][2];   // A, m-half 0
  short8 af1_[4][2];   // A, m-half 1
  short8 bf_[2][2][2]; // B, both n-halves

// pinned-order front-load: group1 = B[h0](4)+A[h0](8), group2 = B[h1](4),
// group3 = A[h1](8). sched_barrier(0) pins group order so counted lgkmcnt
// waits identify exactly these groups.
#define LOADFRAGS(TCUR) do {                                                     \
    const int p_ = (TCUR) & 1;                                                   \
    const u32 a0_ = (u32)(p_ * 16384);                                           \
    const u32 a1_ = (u32)(p_ * 16384 + 8192);                                    \
    const u32 b0_ = (u32)(32768 + p_ * 16384);                                   \
    const u32 b1_ = (u32)(32768 + p_ * 16384 + 8192);                            \
    _Pragma("unroll")                                                            \
    for (int n2 = 0; n2 < 2; ++n2) { const int r_ = wc * 32 + n2 * 16 + llo;     \
      _Pragma("unroll")                                                          \
      for (int kk = 0; kk < 2; ++kk) { const int c_ = kk * 4 + lhi;              \
        bf_[0][n2][kk] = *reinterpret_cast<const short8*>(                       \
            ldsp + b0_ + r_ * 64 + ((c_ ^ (r_ & 7)) * 8)); } }                   \
    _Pragma("unroll")                                                            \
    for (int m4 = 0; m4 < 4; ++m4) { const int r_ = wr * 64 + m4 * 16 + llo;     \
      _Pragma("unroll")                                                          \
      for (int kk = 0; kk < 2; ++kk) { const int c_ = kk * 4 + lhi;              \
        af0_[m4][kk] = *reinterpret_cast<const short8*>(                         \
            ldsp + a0_ + r_ * 64 + ((c_ ^ (r_ & 7)) * 8)); } }                   \
    __builtin_amdgcn_sched_barrier(0);                                           \
    _Pragma("unroll")                                                            \
    for (int n2 = 0; n2 < 2; ++n2) { const int r_ = wc * 32 + n2 * 16 + llo;     \
      _Pragma("unroll")                                                          \
      for (int kk = 0; kk < 2; ++kk) { const int c_ = kk * 4 + lhi;              \
        bf_[1][n2][kk] = *reinterpret_cast<const short8*>(                       \
            ldsp + b1_ + r_ * 64 + ((c_ ^ (r_ & 7)) * 8)); } }                   \
    __builtin_amdgcn_sched_barrier(0);                                           \
    _Pragma("unroll")                                                            \
    for (int m4 = 0; m4 < 4; ++m4) { const int r_ = wr * 64 + m4 * 16 + llo;     \
      _Pragma("unroll")                                                          \
      for (int kk = 0; kk < 2; ++kk) { const int c_ = kk * 4 + lhi;              \
        af1_[m4][kk] = *reinterpret_cast<const short8*>(                         \
            ldsp + a1_ + r_ * 64 + ((c_ ^ (r_ & 7)) * 8)); } }                   \
    __builtin_amdgcn_sched_barrier(0);                                           \
  } while (0)

#define WAITL(n) do {                                                            \
    asm volatile("s_waitcnt lgkmcnt(" #n ")" ::: "memory");                      \
    __builtin_amdgcn_sched_barrier(0);                                           \
  } while (0)

#define STG(TS, H, OPB) stage_half((OPB) ? Bm : Am, (OPB) ? colBase : rowBase,   \
                                   (TS), (H), (OPB))

#define MFMAQ(MH, NH) do {                                                       \
    __builtin_amdgcn_s_setprio(1);                                               \
    _Pragma("unroll")                                                            \
    for (int m4 = 0; m4 < 4; ++m4)                                               \
      _Pragma("unroll")                                                          \
      for (int n2 = 0; n2 < 2; ++n2)                                             \
        _Pragma("unroll")                                                        \
        for (int kk = 0; kk < 2; ++kk)                                           \
          acc[(MH) * 4 + m4][(NH) * 2 + n2] =                                    \
              __builtin_amdgcn_mfma_f32_16x16x32_bf16(                           \
                  (MH) ? af1_[m4][kk] : af0_[m4][kk], bf_[(NH)][n2][kk],         \
                  acc[(MH) * 4 + m4][(NH) * 2 + n2], 0, 0, 0);                   \
    __builtin_amdgcn_s_setprio(0);                                               \
  } while (0)

#define ENDPH(VMN) do {                                                          \
    if ((VMN) == 4) asm volatile("s_waitcnt vmcnt(4)" ::: "memory");             \
    if ((VMN) == 0) asm volatile("s_waitcnt vmcnt(0)" ::: "memory");             \
    __builtin_amdgcn_s_barrier();                                                \
  } while (0)

  // prologue: T0 fully + T1 h0; vmcnt(4) -> T0 fully landed
  stage_half(Am, rowBase, 0, 0, 0);
  stage_half(Bm, colBase, 0, 0, 1);
  stage_half(Am, rowBase, 0, 1, 0);
  stage_half(Bm, colBase, 0, 1, 1);
  stage_half(Am, rowBase, 1, 0, 0);
  stage_half(Bm, colBase, 1, 0, 1);
  asm volatile("s_waitcnt vmcnt(4)" ::: "memory");
  __builtin_amdgcn_s_barrier();

  for (int it = 0; it < 31; ++it) {
    const int T = 2 * it;
    LOADFRAGS(T);
    STG(T + 1, 1, 0); WAITL(12); MFMAQ(0, 0); ENDPH(-1);
    STG(T + 1, 1, 1); WAITL(8);  MFMAQ(0, 1); ENDPH(-1);
    STG(T + 2, 0, 0); WAITL(0);  MFMAQ(1, 0); ENDPH(-1);
    STG(T + 2, 0, 1);            MFMAQ(1, 1); ENDPH(4);
    LOADFRAGS(T + 1);
    STG(T + 2, 1, 0); WAITL(12); MFMAQ(0, 0); ENDPH(-1);
    STG(T + 2, 1, 1); WAITL(8);  MFMAQ(0, 1); ENDPH(-1);
    STG(T + 3, 0, 0); WAITL(0);  MFMAQ(1, 0); ENDPH(-1);
    STG(T + 3, 0, 1);            MFMAQ(1, 1); ENDPH(4);
  }
  // tail pair (62, 63)
  LOADFRAGS(62);
  STG(63, 1, 0); WAITL(12); MFMAQ(0, 0); ENDPH(-1);
  STG(63, 1, 1); WAITL(8);  MFMAQ(0, 1); ENDPH(-1);
                 WAITL(0);  MFMAQ(1, 0); ENDPH(-1);
                            MFMAQ(1, 1); ENDPH(0);   // drain: tile 63 landed
  LOADFRAGS(63);
  WAITL(12); MFMAQ(0, 0); ENDPH(-1);
  WAITL(8);  MFMAQ(0, 1); ENDPH(-1);
  WAITL(0);  MFMAQ(1, 0); ENDPH(-1);
             MFMAQ(1, 1); ENDPH(-1);
#undef LOADFRAGS
#undef WAITL
#undef STG
#undef MFMAQ
#undef ENDPH

  // ---- epilogue: LDS-bounced coalesced stores
  if (OUTF == 1) {
    float* ldf = reinterpret_cast<float*>(ldsp);
    float* Cf = reinterpret_cast<float*>(Cout);
#pragma unroll
    for (int hh = 0; hh < 2; ++hh) {
      if (hh) __syncthreads();
#pragma unroll
      for (int mf2 = 0; mf2 < 4; ++mf2)
#pragma unroll
        for (int nf = 0; nf < 4; ++nf)
#pragma unroll
          for (int r = 0; r < 4; ++r) {
            const int mf = hh * 4 + mf2;
            const int rowL = wr * 64 + mf2 * 16 + lhi * 4 + r;       // 0..127
            const int col = (nf >> 1) * 128 + wc * 32 + (nf & 1) * 16 + llo;
            ldf[rowL * 256 + col] = acc[mf][nf][r] * scl;
          }
      __syncthreads();
#pragma unroll
      for (int k = 0; k < 16; ++k) {
        const int rowL = k * 8 + w;
        const float4 v = *reinterpret_cast<const float4*>(&ldf[rowL * 256 + lane * 4]);
        *reinterpret_cast<float4*>(
            &Cf[(size_t)(rowBase + hh * 128 + rowL) * HDIM + colBase + lane * 4]) = v;
      }
    }
  } else {
#pragma unroll
    for (int mf = 0; mf < 8; ++mf)
#pragma unroll
      for (int nf = 0; nf < 4; ++nf)
#pragma unroll
        for (int r = 0; r < 4; ++r) {
          const int row = (mf >> 2) * 128 + wr * 64 + (mf & 3) * 16 + lhi * 4 + r;
          const int col = (nf >> 1) * 128 + wc * 32 + (nf & 1) * 16 + llo;
          ldsp[row * 256 + col] = f2bf(acc[mf][nf][r] * scl);
        }
    __syncthreads();
    u16* Cb = reinterpret_cast<u16*>(Cout);
#pragma unroll
    for (int k = 0; k < 16; ++k) {
      const int row = k * 16 + w * 2 + (lane >> 5);   // 2 rows/wave, contig 1 KiB
      const int ch = lane & 31;
      if (OUTF == 2) {
        // fused RoPE: pair (d, d+64) within head = col ^ 64 (bit6; head bit7)
        const int R = rowBase + row;
        const int pos = R & (SEQ - 1);
        const int cb = ch * 8;
        const int dl = cb & 63;
        const bool lohalf = (cb & 64) == 0;
        const short8 xv = *reinterpret_cast<const short8*>(&ldsp[row * 256 + cb]);
        const short8 pv = *reinterpret_cast<const short8*>(&ldsp[row * 256 + (cb ^ 64)]);
        const float* cT = &cosT[pos * 64 + dl];
        const float* sT = &sinT[pos * 64 + dl];
        u32 wds[4];
#pragma unroll
        for (int jj = 0; jj < 4; ++jj) {
          const float c0 = cT[jj * 2], c1 = cT[jj * 2 + 1];
          const float s0 = sT[jj * 2], s1 = sT[jj * 2 + 1];
          const float x0 = bf2f((u16)xv[jj * 2]), x1 = bf2f((u16)xv[jj * 2 + 1]);
          const float p0 = bf2f((u16)pv[jj * 2]), p1 = bf2f((u16)pv[jj * 2 + 1]);
          const float o0 = lohalf ? (x0 * c0 - p0 * s0) : (x0 * c0 + p0 * s0);
          const float o1 = lohalf ? (x1 * c1 - p1 * s1) : (x1 * c1 + p1 * s1);
          wds[jj] = pack2(o0, o1);
        }
        uint4 ov = make_uint4(wds[0], wds[1], wds[2], wds[3]);
        *reinterpret_cast<uint4*>(&Cb[(size_t)R * HDIM + colBase + cb]) = ov;
      } else {
        const short8 v = *reinterpret_cast<const short8*>(&ldsp[row * 256 + ch * 8]);
        *reinterpret_cast<short8*>(&Cb[(size_t)(rowBase + row) * HDIM + colBase + ch * 8]) = v;
      }
    }
  }
}

// ---------------- flash-causal attention ----------------
// Grid (8, 64); block x does q-tiles x and 15-x (triangle fold, equal work).
// KVBLK=64. K/V via XOR-source-swizzled global_load_lds; counted vmcnt(2)
// keeps K(t+1) in flight over the mid-tile publish barrier.
// Swapped QK^T: lane owns q-row llo; in-lane softmax + 2 shfl_xor.
__global__ __launch_bounds__(512, 4)
void attn_causal(const u16* __restrict__ Q, const u16* __restrict__ K,
                 const u16* __restrict__ VT, u16* __restrict__ O) {
  __shared__ __align__(16) u16 Ks[2][64][128];
  __shared__ __align__(16) u16 Vt[128][64];
  __shared__ __align__(16) u16 Pw[8][16][76];

  const int tid = threadIdx.x;
  const int w = tid >> 6, lane = tid & 63;
  const int lhi = lane >> 4, llo = lane & 15;
  const int bh = blockIdx.y, b = bh >> 5, h = bh & 31;

  const u16* Kg = K + ((size_t)b * SEQ) * HDIM + h * DHEAD;
  const u16* VTg = VT + (size_t)(h * DHEAD) * NROWS + b * SEQ;   // [d][s], stride NROWS

  const int kcp = tid & 15;                 // K staging chunk (16 per row)
  const int vrl = tid >> 3, vcp = tid & 7;  // V staging: row-low, chunk (8 per row)

  const float smul2 = 0.127517427f;         // (1/sqrt(128)) * log2(e)

  for (int halfq = 0; halfq < 2; ++halfq) {
    const int xq = (halfq == 0) ? (int)blockIdx.x : 15 - (int)blockIdx.x;
    const int qb = xq * QBLK;
    const int ntile = qb / 64 + 2;
    const int wmax = qb + w * 16 + 15;
    const int qrow = qb + w * 16 + llo;     // lane-owned q-row (swapped layout)

    const u16* Qg = Q + ((size_t)(b * SEQ + qb)) * HDIM + h * DHEAD;
    short8 qf[4];
#pragma unroll
    for (int dc = 0; dc < 4; ++dc)
      qf[dc] = *reinterpret_cast<const short8*>(Qg + (size_t)(w * 16 + llo) * HDIM + dc * 32 + lhi * 8);

    f32x4 o[8];
#pragma unroll
    for (int dt = 0; dt < 8; ++dt) o[dt] = (f32x4)0.0f;
    float mrow = -__builtin_inff(), lrow = 0.0f;

    // prologue: K(0) -> Ks[0]
    {
      u16* dst = &Ks[0][0][0] + tid * 8;
#pragma unroll
      for (int i = 0; i < 2; ++i) {
        const int r = i * 32 + (tid >> 4);
        const int cs = kcp ^ (r & 7);
        gload16(Kg + (size_t)r * HDIM + cs * 8, dst + i * 4096);
      }
    }
    __syncthreads();
    int buf = 0;

    for (int t = 0; t < ntile; ++t) {
      const int kv0 = t * 64;
      // issue V(t) -> Vt (single buffer; readers of V(t-1) joined at tile end)
      {
        u16* dst = &Vt[0][0] + tid * 8;
#pragma unroll
        for (int i = 0; i < 2; ++i) {
          const int rV = i * 64 + vrl;
          const int cs = vcp ^ (rV & 7);
          gload16(VTg + (size_t)rV * NROWS + kv0 + cs * 8, dst + i * 4096);
        }
      }
      const bool haveK = (t + 1 < ntile);
      if (haveK) {
        u16* dst = &Ks[buf ^ 1][0][0] + tid * 8;
        const int nkv = kv0 + 64;
#pragma unroll
        for (int i = 0; i < 2; ++i) {
          const int r = i * 32 + (tid >> 4);
          const int cs = kcp ^ (r & 7);
          gload16(Kg + (size_t)(nkv + r) * HDIM + cs * 8, dst + i * 4096);
        }
      }

      const bool docomp = (kv0 <= wmax);
      union { short4v hh[2]; short8 v8; } pu[2];
      if (docomp) {
        f32x4 sacc[4];
#pragma unroll
        for (int nt2 = 0; nt2 < 4; ++nt2) sacc[nt2] = (f32x4)0.0f;
        __builtin_amdgcn_s_setprio(1);
#pragma unroll
        for (int nt2 = 0; nt2 < 4; ++nt2) {
          const int r = nt2 * 16 + llo;
#pragma unroll
          for (int dc = 0; dc < 4; ++dc) {
            const int cs = (dc * 4 + lhi) ^ (r & 7);
            const short8 kf = *reinterpret_cast<const short8*>(&Ks[buf][r][cs * 8]);
            // SWAPPED: A=K (row=llo -> kcol), B=Q (col=llo -> qrow)
            sacc[nt2] = __builtin_amdgcn_mfma_f32_16x16x32_bf16(kf, qf[dc], sacc[nt2], 0, 0, 0);
          }
        }
        __builtin_amdgcn_s_setprio(0);

        // lane holds S[qrow][kcol = kv0 + nt2*16 + lhi*4 + i]
        const int thr = qrow - kv0 - lhi * 4;   // mask: nt2*16 + i <= thr
        float sv[4][4];
#pragma unroll
        for (int nt2 = 0; nt2 < 4; ++nt2)
#pragma unroll
          for (int i = 0; i < 4; ++i) {
            const float xv = sacc[nt2][i] * smul2;
            sv[nt2][i] = (nt2 * 16 + i <= thr) ? xv : -__builtin_inff();
          }

        // in-lane max over 16, then combine across the 4 lhi-lanes (same llo)
        float rmax = sv[0][0];
#pragma unroll
        for (int nt2 = 0; nt2 < 4; ++nt2)
#pragma unroll
          for (int i = 0; i < 4; ++i) rmax = fmaxf(rmax, sv[nt2][i]);
        rmax = fmaxf(rmax, __shfl_xor(rmax, 16));
        rmax = fmaxf(rmax, __shfl_xor(rmax, 32));

        // narrow defer-max: only the rescale is guarded
        const bool need = (rmax > mrow + 8.0f);
        if (__any((int)need)) {
          const float mn = fmaxf(mrow, rmax);
          const float facl = exp2v(mrow - mn);
          mrow = mn;
          lrow *= facl;
          float facr[4];
#pragma unroll
          for (int r = 0; r < 4; ++r) facr[r] = __shfl(facl, lhi * 4 + r);
#pragma unroll
          for (int dt = 0; dt < 8; ++dt)
#pragma unroll
            for (int r = 0; r < 4; ++r) o[dt][r] *= facr[r];
        }

        float p[4][4];
        float rsum = 0.0f;
#pragma unroll
        for (int nt2 = 0; nt2 < 4; ++nt2)
#pragma unroll
          for (int i = 0; i < 4; ++i) {
            p[nt2][i] = exp2v(sv[nt2][i] - mrow);
            rsum += p[nt2][i];
          }
        rsum += __shfl_xor(rsum, 16);
        rsum += __shfl_xor(rsum, 32);
        lrow += rsum;

        // P -> Pw[qrow=llo][kcol]; each lane writes its 16 owned kcols
#pragma unroll
        for (int nt2 = 0; nt2 < 4; ++nt2)
#pragma unroll
          for (int i = 0; i < 4; ++i)
            Pw[w][llo][nt2 * 16 + lhi * 4 + i] = f2bf_t(p[nt2][i]);

#pragma unroll
        for (int s = 0; s < 2; ++s) {
          pu[s].hh[0] = *reinterpret_cast<const short4v*>(&Pw[w][llo][s * 32 + lhi * 8]);
          pu[s].hh[1] = *reinterpret_cast<const short4v*>(&Pw[w][llo][s * 32 + lhi * 8 + 4]);
        }
      }

      // publish V(t): each wave waits its own V loads (2 oldest), then joins.
      if (haveK) asm volatile("s_waitcnt vmcnt(2)" ::: "memory");
      else       asm volatile("s_waitcnt vmcnt(0)" ::: "memory");
      __builtin_amdgcn_s_barrier();

      if (docomp) {
        __builtin_amdgcn_s_setprio(1);
#pragma unroll
        for (int dt = 0; dt < 8; ++dt)
#pragma unroll
          for (int s = 0; s < 2; ++s) {
            const int rr = dt * 16 + llo;
            const int cs = (s * 4 + lhi) ^ (rr & 7);
            const short8 vf = *reinterpret_cast<const short8*>(&Vt[rr][cs * 8]);
            o[dt] = __builtin_amdgcn_mfma_f32_16x16x32_bf16(pu[s].v8, vf, o[dt], 0, 0, 0);
          }
        __builtin_amdgcn_s_setprio(0);
      }
      __syncthreads();   // joins waves; drains K(t+1) (issued a full tile ago)
      buf ^= 1;
    }

    u16* Og = O + ((size_t)(b * SEQ + qb)) * HDIM + h * DHEAD;
    float invr[4];
#pragma unroll
    for (int r = 0; r < 4; ++r) invr[r] = 1.0f / __shfl(lrow, lhi * 4 + r);
#pragma unroll
    for (int dt = 0; dt < 8; ++dt)
#pragma unroll
      for (int r = 0; r < 4; ++r)
        Og[(size_t)(w * 16 + lhi * 4 + r) * HDIM + dt * 16 + llo] = f2bf(o[dt][r] * invr[r]);
  }
}

// ---------------- launch ----------------
extern "C" void kernel_launch(void* const* d_in, const int* in_sizes, int n_in,
                              void* d_out, int out_size, void* d_ws, size_t ws_size,
                              hipStream_t stream) {
  (void)in_sizes; (void)n_in; (void)out_size; (void)ws_size;
  const float* hs = (const float*)d_in[0];
  const float* wq = (const float*)d_in[2];
  const float* wk = (const float*)d_in[3];
  const float* wv = (const float*)d_in[4];
  const float* wo = (const float*)d_in[5];
  const float* sq = (const float*)d_in[6];
  const float* sk = (const float*)d_in[7];
  const float* sv = (const float*)d_in[8];
  const float* so = (const float*)d_in[9];

  char* p = (char*)d_ws;
  const size_t MAT = (size_t)NROWS * HDIM * sizeof(u16);  // 32 MiB
  u16* Xb = (u16*)p; p += MAT;   // X bf16; later attention output
  u16* Wb = (u16*)p; p += MAT;   // weight bf16 slot (reused 4x)
  u16* Qb = (u16*)p; p += MAT;
  u16* Kb = (u16*)p; p += MAT;
  u16* Vb = (u16*)p; p += MAT;   // holds V^T (operand-swapped GEMM output)
  float* cosT = (float*)p; p += (size_t)SEQ * 64 * sizeof(float);
  float* sinT = (float*)p; p += (size_t)SEQ * 64 * sizeof(float);

  const int n4 = NROWS * (HDIM / 4);
  const dim3 cb(256);
  const int LDSZ = 131072;  // 128 KiB dynamic LDS for gemm8
  (void)hipFuncSetAttribute(reinterpret_cast<const void*>(&gemm8<0>),
                            hipFuncAttributeMaxDynamicSharedMemorySize, LDSZ);
  (void)hipFuncSetAttribute(reinterpret_cast<const void*>(&gemm8<1>),
                            hipFuncAttributeMaxDynamicSharedMemorySize, LDSZ);
  (void)hipFuncSetAttribute(reinterpret_cast<const void*>(&gemm8<2>),
                            hipFuncAttributeMaxDynamicSharedMemorySize, LDSZ);

  f2bf_vec<<<dim3(2048), cb, 0, stream>>>(hs, Xb, n4);
  rope_tables_k<<<dim3((SEQ * 64 + 255) / 256), cb, 0, stream>>>(cosT, sinT);

  f2bf_vec<<<dim3(2048), cb, 0, stream>>>(wq, Wb, n4);
  gemm8<2><<<dim3(256), dim3(512), LDSZ, stream>>>(Xb, Wb, (void*)Qb, sq, cosT, sinT);
  f2bf_vec<<<dim3(2048), cb, 0, stream>>>(wk, Wb, n4);
  gemm8<2><<<dim3(256), dim3(512), LDSZ, stream>>>(Xb, Wb, (void*)Kb, sk, cosT, sinT);
  f2bf_vec<<<dim3(2048), cb, 0, stream>>>(wv, Wb, n4);
  // operand-swapped: C[o][r] = sum_k Wv[o][k] X[r][k] = V^T  (into Vb)
  gemm8<0><<<dim3(256), dim3(512), LDSZ, stream>>>(Wb, Xb, (void*)Vb, sv, cosT, sinT);

  attn_causal<<<dim3(8, NBATCH * NHEADS), dim3(512), 0, stream>>>(Qb, Kb, Vb, Xb);

  f2bf_vec<<<dim3(2048), cb, 0, stream>>>(wo, Wb, n4);
  gemm8<1><<<dim3(256), dim3(512), LDSZ, stream>>>(Xb, Wb, d_out, so, cosT, sinT);
}

// Round 17
// 628.399 us; speedup vs baseline: 2.2162x; 2.2162x over previous
//
#include <hip/hip_runtime.h>
#include <stdint.h>
#include <math.h>

// BitNetAttention on MI355X (gfx950), round 16: REVERT gemm8 to R14 state.
// R15's fully-front-loaded fragments (af0+af1+bf = 96 VGPR live + 128 acc)
// blew the register budget -> per-K-tile scratch spills (WRITE 35.8->204 MB,
// FETCH 103->328 MB, 330 us/gemm). R13/R14's partial register-carry (bf_
// held, af_ reloaded per m-half) is the register-feasible schedule.
// Attn (R12 swapped-QK + R11 staging), RoPE-fused epilogue, converts
// unchanged.

#define HDIM   4096
#define SEQ    2048
#define NBATCH 2
#define NROWS  (NBATCH * SEQ)   // 4096
#define NHEADS 32
#define DHEAD  128
#define QBLK   128

typedef __attribute__((ext_vector_type(8))) short short8;
typedef __attribute__((ext_vector_type(4))) short short4v;
typedef __attribute__((ext_vector_type(4))) float f32x4;
typedef unsigned short u16;
typedef unsigned int   u32;

__device__ __forceinline__ float bf2f(u16 u) {
  union { float f; u32 i; } x; x.i = ((u32)u) << 16; return x.f;
}
__device__ __forceinline__ u16 f2bf(float f) {
  union { float f; u32 i; } x; x.f = f;
  u32 r = x.i + 0x7FFFu + ((x.i >> 16) & 1u);   // RNE
  return (u16)(r >> 16);
}
__device__ __forceinline__ u16 f2bf_t(float f) {   // truncating (cheap)
  union { float f; u32 i; } x; x.f = f;
  return (u16)(x.i >> 16);
}
// bare hardware exp2 (1 instr; FTZ + exp2(-inf)=0 fine for softmax domain)
__device__ __forceinline__ float exp2v(float x) {
  float r; asm("v_exp_f32 %0, %1" : "=v"(r) : "v"(x)); return r;
}

__device__ __forceinline__ void gload16(const u16* g, u16* l) {
  __builtin_amdgcn_global_load_lds(
      (const __attribute__((address_space(1))) u32*)g,
      (__attribute__((address_space(3))) u32*)l, 16, 0, 0);
}

__device__ __forceinline__ void unpack2(u32 v, float& a, float& b) {
  a = bf2f((u16)(v & 0xffffu)); b = bf2f((u16)(v >> 16));
}
__device__ __forceinline__ u32 pack2(float a, float b) {
  return (u32)f2bf(a) | ((u32)f2bf(b) << 16);
}

// ---------------- fp32 -> bf16 convert (vectorized) ----------------
__global__ void f2bf_vec(const float* __restrict__ in, u16* __restrict__ out, int n4) {
  int i = blockIdx.x * blockDim.x + threadIdx.x;
  const int stride = gridDim.x * blockDim.x;
  for (; i < n4; i += stride) {
    float4 v = reinterpret_cast<const float4*>(in)[i];
    u32 lo = (u32)f2bf(v.x) | ((u32)f2bf(v.y) << 16);
    u32 hi = (u32)f2bf(v.z) | ((u32)f2bf(v.w) << 16);
    reinterpret_cast<uint2*>(out)[i] = make_uint2(lo, hi);
  }
}

// ---------------- RoPE tables [SEQ][64] fp32 ----------------
__global__ void rope_tables_k(float* __restrict__ cosT, float* __restrict__ sinT) {
  int idx = blockIdx.x * blockDim.x + threadIdx.x;
  if (idx >= SEQ * 64) return;
  int s = idx >> 6, d = idx & 63;
  float ex = (float)(2 * d) / 128.0f;
  float inv = powf(10000.0f, -ex);
  float f = (float)s * inv;
  cosT[idx] = cosf(f);
  sinT[idx] = sinf(f);
}

// ---------------- 8-phase GEMM: C[4096][4096] = (A * B^T) * scale ----------------
// OUTF: 0 = bf16 out, 1 = fp32 out, 2 = bf16 out + fused RoPE (Q/K GEMMs).
template<int OUTF>
__global__ __launch_bounds__(512, 2)
void gemm8(const u16* __restrict__ Am, const u16* __restrict__ Bm,
           void* __restrict__ Cout, const float* __restrict__ scale_ptr,
           const float* __restrict__ cosT, const float* __restrict__ sinT) {
  extern __shared__ __align__(16) u16 ldsp[];

  const int tid = threadIdx.x;
  const int w = tid >> 6, lane = tid & 63;
  const int llo = lane & 15, lhi = (lane >> 4) & 3;
  const int wr = w >> 2, wc = w & 3;           // 2 x 4 waves

  const int bid = blockIdx.x;
  const int xcd = bid & 7, ii = bid >> 3;
  const int by = (xcd >> 1) * 4 + (ii & 3);
  const int bx = (xcd & 1) * 8 + (ii >> 2);
  const int rowBase = by * 256, colBase = bx * 256;
  const float scl = scale_ptr[0];

  auto stage_half = [&](const u16* G, int obase, int ts, int h, int opB) {
    const int p = ts & 1;
    const u32 base = (opB ? 32768u : 0u) + (u32)p * 16384u + (u32)h * 8192u;
#pragma unroll
    for (int i = 0; i < 2; ++i) {
      const int ru = i * 64 + w * 8;
      const int r = ru + (lane >> 3);
      const int cc = (lane & 7) ^ (r & 7);
      gload16(G + (size_t)(obase + h * 128 + r) * HDIM + ts * 64 + cc * 8,
              ldsp + base + (u32)ru * 64u);
    }
  };

  f32x4 acc[8][4];
#pragma unroll
  for (int m = 0; m < 8; ++m)
#pragma unroll
    for (int n = 0; n < 4; ++n) acc[m][n] = (f32x4)0.0f;

  // fragment registers carried across phases (register-feasible set):
  // af_: A fragments for current MH (reloaded ph1/ph3); bf_[NH]: held.
  short8 af_[4][2];
  short8 bf_[2][2][2];

// One barrier per phase: loads/stage -> lgkm(0)+sched_barrier -> MFMA ->
// [vmcnt] -> s_barrier. LA/LB: load A/B fragments this phase.
#define PH(TCUR, MH, NH, LA, LB, TS, H, OPB, DOSTAGE, VMN) do {                  \
    const int p_ = (TCUR) & 1;                                                   \
    const u32 ab_ = (u32)(p_ * 16384 + (MH) * 8192);                             \
    const u32 bb_ = (u32)(32768 + p_ * 16384 + (NH) * 8192);                     \
    if (LA) {                                                                    \
      _Pragma("unroll")                                                          \
      for (int m4 = 0; m4 < 4; ++m4) { const int r_ = wr * 64 + m4 * 16 + llo;   \
        _Pragma("unroll")                                                        \
        for (int kk = 0; kk < 2; ++kk) { const int c_ = kk * 4 + lhi;            \
          af_[m4][kk] = *reinterpret_cast<const short8*>(                        \
              ldsp + ab_ + r_ * 64 + ((c_ ^ (r_ & 7)) * 8)); } }                 \
    }                                                                            \
    if (LB) {                                                                    \
      _Pragma("unroll")                                                          \
      for (int n2 = 0; n2 < 2; ++n2) { const int r_ = wc * 32 + n2 * 16 + llo;   \
        _Pragma("unroll")                                                        \
        for (int kk = 0; kk < 2; ++kk) { const int c_ = kk * 4 + lhi;            \
          bf_[NH][n2][kk] = *reinterpret_cast<const short8*>(                    \
              ldsp + bb_ + r_ * 64 + ((c_ ^ (r_ & 7)) * 8)); } }                 \
    }                                                                            \
    if (DOSTAGE) stage_half((OPB) ? Bm : Am, (OPB) ? colBase : rowBase,          \
                            (TS), (H), (OPB));                                   \
    asm volatile("s_waitcnt lgkmcnt(0)" ::: "memory");                           \
    __builtin_amdgcn_sched_barrier(0);                                           \
    __builtin_amdgcn_s_setprio(1);                                               \
    _Pragma("unroll")                                                            \
    for (int m4 = 0; m4 < 4; ++m4)                                               \
      _Pragma("unroll")                                                          \
      for (int n2 = 0; n2 < 2; ++n2)                                             \
        _Pragma("unroll")                                                        \
        for (int kk = 0; kk < 2; ++kk)                                           \
          acc[(MH) * 4 + m4][(NH) * 2 + n2] =                                    \
              __builtin_amdgcn_mfma_f32_16x16x32_bf16(                           \
                  af_[m4][kk], bf_[(NH)][n2][kk],                                \
                  acc[(MH) * 4 + m4][(NH) * 2 + n2], 0, 0, 0);                   \
    __builtin_amdgcn_s_setprio(0);                                               \
    if ((VMN) == 4) asm volatile("s_waitcnt vmcnt(4)" ::: "memory");             \
    if ((VMN) == 0) asm volatile("s_waitcnt vmcnt(0)" ::: "memory");             \
    __builtin_amdgcn_s_barrier();                                                \
  } while (0)

  stage_half(Am, rowBase, 0, 0, 0);
  stage_half(Bm, colBase, 0, 0, 1);
  stage_half(Am, rowBase, 0, 1, 0);
  stage_half(Bm, colBase, 0, 1, 1);
  stage_half(Am, rowBase, 1, 0, 0);
  stage_half(Bm, colBase, 1, 0, 1);
  asm volatile("s_waitcnt vmcnt(4)" ::: "memory");
  __builtin_amdgcn_s_barrier();

  for (int it = 0; it < 31; ++it) {
    const int T = 2 * it;
    PH(T,     0, 0, 1, 1, T + 1, 1, 0, 1, -1);
    PH(T,     0, 1, 0, 1, T + 1, 1, 1, 1, -1);
    PH(T,     1, 0, 1, 0, T + 2, 0, 0, 1, -1);
    PH(T,     1, 1, 0, 0, T + 2, 0, 1, 1,  4);
    PH(T + 1, 0, 0, 1, 1, T + 2, 1, 0, 1, -1);
    PH(T + 1, 0, 1, 0, 1, T + 2, 1, 1, 1, -1);
    PH(T + 1, 1, 0, 1, 0, T + 3, 0, 0, 1, -1);
    PH(T + 1, 1, 1, 0, 0, T + 3, 0, 1, 1,  4);
  }
  PH(62, 0, 0, 1, 1, 63, 1, 0, 1, -1);
  PH(62, 0, 1, 0, 1, 63, 1, 1, 1, -1);
  PH(62, 1, 0, 1, 0,  0, 0, 0, 0, -1);
  PH(62, 1, 1, 0, 0,  0, 0, 0, 0,  0);
  PH(63, 0, 0, 1, 1,  0, 0, 0, 0, -1);
  PH(63, 0, 1, 0, 1,  0, 0, 0, 0, -1);
  PH(63, 1, 0, 1, 0,  0, 0, 0, 0, -1);
  PH(63, 1, 1, 0, 0,  0, 0, 0, 0, -1);
#undef PH

  // ---- epilogue: LDS-bounced coalesced stores
  if (OUTF == 1) {
    float* ldf = reinterpret_cast<float*>(ldsp);
    float* Cf = reinterpret_cast<float*>(Cout);
#pragma unroll
    for (int hh = 0; hh < 2; ++hh) {
      if (hh) __syncthreads();
#pragma unroll
      for (int mf2 = 0; mf2 < 4; ++mf2)
#pragma unroll
        for (int nf = 0; nf < 4; ++nf)
#pragma unroll
          for (int r = 0; r < 4; ++r) {
            const int mf = hh * 4 + mf2;
            const int rowL = wr * 64 + mf2 * 16 + lhi * 4 + r;       // 0..127
            const int col = (nf >> 1) * 128 + wc * 32 + (nf & 1) * 16 + llo;
            ldf[rowL * 256 + col] = acc[mf][nf][r] * scl;
          }
      __syncthreads();
#pragma unroll
      for (int k = 0; k < 16; ++k) {
        const int rowL = k * 8 + w;
        const float4 v = *reinterpret_cast<const float4*>(&ldf[rowL * 256 + lane * 4]);
        *reinterpret_cast<float4*>(
            &Cf[(size_t)(rowBase + hh * 128 + rowL) * HDIM + colBase + lane * 4]) = v;
      }
    }
  } else {
#pragma unroll
    for (int mf = 0; mf < 8; ++mf)
#pragma unroll
      for (int nf = 0; nf < 4; ++nf)
#pragma unroll
        for (int r = 0; r < 4; ++r) {
          const int row = (mf >> 2) * 128 + wr * 64 + (mf & 3) * 16 + lhi * 4 + r;
          const int col = (nf >> 1) * 128 + wc * 32 + (nf & 1) * 16 + llo;
          ldsp[row * 256 + col] = f2bf(acc[mf][nf][r] * scl);
        }
    __syncthreads();
    u16* Cb = reinterpret_cast<u16*>(Cout);
#pragma unroll
    for (int k = 0; k < 16; ++k) {
      const int row = k * 16 + w * 2 + (lane >> 5);   // 2 rows/wave, contig 1 KiB
      const int ch = lane & 31;
      if (OUTF == 2) {
        // fused RoPE: pair (d, d+64) within head = col ^ 64 (bit6; head bit7)
        const int R = rowBase + row;
        const int pos = R & (SEQ - 1);
        const int cb = ch * 8;
        const int dl = cb & 63;
        const bool lohalf = (cb & 64) == 0;
        const short8 xv = *reinterpret_cast<const short8*>(&ldsp[row * 256 + cb]);
        const short8 pv = *reinterpret_cast<const short8*>(&ldsp[row * 256 + (cb ^ 64)]);
        const float* cT = &cosT[pos * 64 + dl];
        const float* sT = &sinT[pos * 64 + dl];
        u32 wds[4];
#pragma unroll
        for (int jj = 0; jj < 4; ++jj) {
          const float c0 = cT[jj * 2], c1 = cT[jj * 2 + 1];
          const float s0 = sT[jj * 2], s1 = sT[jj * 2 + 1];
          const float x0 = bf2f((u16)xv[jj * 2]), x1 = bf2f((u16)xv[jj * 2 + 1]);
          const float p0 = bf2f((u16)pv[jj * 2]), p1 = bf2f((u16)pv[jj * 2 + 1]);
          const float o0 = lohalf ? (x0 * c0 - p0 * s0) : (x0 * c0 + p0 * s0);
          const float o1 = lohalf ? (x1 * c1 - p1 * s1) : (x1 * c1 + p1 * s1);
          wds[jj] = pack2(o0, o1);
        }
        uint4 ov = make_uint4(wds[0], wds[1], wds[2], wds[3]);
        *reinterpret_cast<uint4*>(&Cb[(size_t)R * HDIM + colBase + cb]) = ov;
      } else {
        const short8 v = *reinterpret_cast<const short8*>(&ldsp[row * 256 + ch * 8]);
        *reinterpret_cast<short8*>(&Cb[(size_t)(rowBase + row) * HDIM + colBase + ch * 8]) = v;
      }
    }
  }
}

// ---------------- flash-causal attention ----------------
// Grid (8, 64); block x does q-tiles x and 15-x (triangle fold, equal work).
// KVBLK=64. K/V via XOR-source-swizzled global_load_lds; counted vmcnt(2)
// keeps K(t+1) in flight over the mid-tile publish barrier.
// Swapped QK^T: lane owns q-row llo; in-lane softmax + 2 shfl_xor.
__global__ __launch_bounds__(512, 4)
void attn_causal(const u16* __restrict__ Q, const u16* __restrict__ K,
                 const u16* __restrict__ VT, u16* __restrict__ O) {
  __shared__ __align__(16) u16 Ks[2][64][128];
  __shared__ __align__(16) u16 Vt[128][64];
  __shared__ __align__(16) u16 Pw[8][16][76];

  const int tid = threadIdx.x;
  const int w = tid >> 6, lane = tid & 63;
  const int lhi = lane >> 4, llo = lane & 15;
  const int bh = blockIdx.y, b = bh >> 5, h = bh & 31;

  const u16* Kg = K + ((size_t)b * SEQ) * HDIM + h * DHEAD;
  const u16* VTg = VT + (size_t)(h * DHEAD) * NROWS + b * SEQ;   // [d][s], stride NROWS

  const int kcp = tid & 15;                 // K staging chunk (16 per row)
  const int vrl = tid >> 3, vcp = tid & 7;  // V staging: row-low, chunk (8 per row)

  const float smul2 = 0.127517427f;         // (1/sqrt(128)) * log2(e)

  for (int halfq = 0; halfq < 2; ++halfq) {
    const int xq = (halfq == 0) ? (int)blockIdx.x : 15 - (int)blockIdx.x;
    const int qb = xq * QBLK;
    const int ntile = qb / 64 + 2;
    const int wmax = qb + w * 16 + 15;
    const int qrow = qb + w * 16 + llo;     // lane-owned q-row (swapped layout)

    const u16* Qg = Q + ((size_t)(b * SEQ + qb)) * HDIM + h * DHEAD;
    short8 qf[4];
#pragma unroll
    for (int dc = 0; dc < 4; ++dc)
      qf[dc] = *reinterpret_cast<const short8*>(Qg + (size_t)(w * 16 + llo) * HDIM + dc * 32 + lhi * 8);

    f32x4 o[8];
#pragma unroll
    for (int dt = 0; dt < 8; ++dt) o[dt] = (f32x4)0.0f;
    float mrow = -__builtin_inff(), lrow = 0.0f;

    // prologue: K(0) -> Ks[0]
    {
      u16* dst = &Ks[0][0][0] + tid * 8;
#pragma unroll
      for (int i = 0; i < 2; ++i) {
        const int r = i * 32 + (tid >> 4);
        const int cs = kcp ^ (r & 7);
        gload16(Kg + (size_t)r * HDIM + cs * 8, dst + i * 4096);
      }
    }
    __syncthreads();
    int buf = 0;

    for (int t = 0; t < ntile; ++t) {
      const int kv0 = t * 64;
      // issue V(t) -> Vt (single buffer; readers of V(t-1) joined at tile end)
      {
        u16* dst = &Vt[0][0] + tid * 8;
#pragma unroll
        for (int i = 0; i < 2; ++i) {
          const int rV = i * 64 + vrl;
          const int cs = vcp ^ (rV & 7);
          gload16(VTg + (size_t)rV * NROWS + kv0 + cs * 8, dst + i * 4096);
        }
      }
      const bool haveK = (t + 1 < ntile);
      if (haveK) {
        u16* dst = &Ks[buf ^ 1][0][0] + tid * 8;
        const int nkv = kv0 + 64;
#pragma unroll
        for (int i = 0; i < 2; ++i) {
          const int r = i * 32 + (tid >> 4);
          const int cs = kcp ^ (r & 7);
          gload16(Kg + (size_t)(nkv + r) * HDIM + cs * 8, dst + i * 4096);
        }
      }

      const bool docomp = (kv0 <= wmax);
      union { short4v hh[2]; short8 v8; } pu[2];
      if (docomp) {
        f32x4 sacc[4];
#pragma unroll
        for (int nt2 = 0; nt2 < 4; ++nt2) sacc[nt2] = (f32x4)0.0f;
        __builtin_amdgcn_s_setprio(1);
#pragma unroll
        for (int nt2 = 0; nt2 < 4; ++nt2) {
          const int r = nt2 * 16 + llo;
#pragma unroll
          for (int dc = 0; dc < 4; ++dc) {
            const int cs = (dc * 4 + lhi) ^ (r & 7);
            const short8 kf = *reinterpret_cast<const short8*>(&Ks[buf][r][cs * 8]);
            // SWAPPED: A=K (row=llo -> kcol), B=Q (col=llo -> qrow)
            sacc[nt2] = __builtin_amdgcn_mfma_f32_16x16x32_bf16(kf, qf[dc], sacc[nt2], 0, 0, 0);
          }
        }
        __builtin_amdgcn_s_setprio(0);

        // lane holds S[qrow][kcol = kv0 + nt2*16 + lhi*4 + i]
        const int thr = qrow - kv0 - lhi * 4;   // mask: nt2*16 + i <= thr
        float sv[4][4];
#pragma unroll
        for (int nt2 = 0; nt2 < 4; ++nt2)
#pragma unroll
          for (int i = 0; i < 4; ++i) {
            const float xv = sacc[nt2][i] * smul2;
            sv[nt2][i] = (nt2 * 16 + i <= thr) ? xv : -__builtin_inff();
          }

        // in-lane max over 16, then combine across the 4 lhi-lanes (same llo)
        float rmax = sv[0][0];
#pragma unroll
        for (int nt2 = 0; nt2 < 4; ++nt2)
#pragma unroll
          for (int i = 0; i < 4; ++i) rmax = fmaxf(rmax, sv[nt2][i]);
        rmax = fmaxf(rmax, __shfl_xor(rmax, 16));
        rmax = fmaxf(rmax, __shfl_xor(rmax, 32));

        // narrow defer-max: only the rescale is guarded
        const bool need = (rmax > mrow + 8.0f);
        if (__any((int)need)) {
          const float mn = fmaxf(mrow, rmax);
          const float facl = exp2v(mrow - mn);
          mrow = mn;
          lrow *= facl;
          float facr[4];
#pragma unroll
          for (int r = 0; r < 4; ++r) facr[r] = __shfl(facl, lhi * 4 + r);
#pragma unroll
          for (int dt = 0; dt < 8; ++dt)
#pragma unroll
            for (int r = 0; r < 4; ++r) o[dt][r] *= facr[r];
        }

        float p[4][4];
        float rsum = 0.0f;
#pragma unroll
        for (int nt2 = 0; nt2 < 4; ++nt2)
#pragma unroll
          for (int i = 0; i < 4; ++i) {
            p[nt2][i] = exp2v(sv[nt2][i] - mrow);
            rsum += p[nt2][i];
          }
        rsum += __shfl_xor(rsum, 16);
        rsum += __shfl_xor(rsum, 32);
        lrow += rsum;

        // P -> Pw[qrow=llo][kcol]; each lane writes its 16 owned kcols
#pragma unroll
        for (int nt2 = 0; nt2 < 4; ++nt2)
#pragma unroll
          for (int i = 0; i < 4; ++i)
            Pw[w][llo][nt2 * 16 + lhi * 4 + i] = f2bf_t(p[nt2][i]);

#pragma unroll
        for (int s = 0; s < 2; ++s) {
          pu[s].hh[0] = *reinterpret_cast<const short4v*>(&Pw[w][llo][s * 32 + lhi * 8]);
          pu[s].hh[1] = *reinterpret_cast<const short4v*>(&Pw[w][llo][s * 32 + lhi * 8 + 4]);
        }
      }

      // publish V(t): each wave waits its own V loads (2 oldest), then joins.
      if (haveK) asm volatile("s_waitcnt vmcnt(2)" ::: "memory");
      else       asm volatile("s_waitcnt vmcnt(0)" ::: "memory");
      __builtin_amdgcn_s_barrier();

      if (docomp) {
        __builtin_amdgcn_s_setprio(1);
#pragma unroll
        for (int dt = 0; dt < 8; ++dt)
#pragma unroll
          for (int s = 0; s < 2; ++s) {
            const int rr = dt * 16 + llo;
            const int cs = (s * 4 + lhi) ^ (rr & 7);
            const short8 vf = *reinterpret_cast<const short8*>(&Vt[rr][cs * 8]);
            o[dt] = __builtin_amdgcn_mfma_f32_16x16x32_bf16(pu[s].v8, vf, o[dt], 0, 0, 0);
          }
        __builtin_amdgcn_s_setprio(0);
      }
      __syncthreads();   // joins waves; drains K(t+1) (issued a full tile ago)
      buf ^= 1;
    }

    u16* Og = O + ((size_t)(b * SEQ + qb)) * HDIM + h * DHEAD;
    float invr[4];
#pragma unroll
    for (int r = 0; r < 4; ++r) invr[r] = 1.0f / __shfl(lrow, lhi * 4 + r);
#pragma unroll
    for (int dt = 0; dt < 8; ++dt)
#pragma unroll
      for (int r = 0; r < 4; ++r)
        Og[(size_t)(w * 16 + lhi * 4 + r) * HDIM + dt * 16 + llo] = f2bf(o[dt][r] * invr[r]);
  }
}

// ---------------- launch ----------------
extern "C" void kernel_launch(void* const* d_in, const int* in_sizes, int n_in,
                              void* d_out, int out_size, void* d_ws, size_t ws_size,
                              hipStream_t stream) {
  (void)in_sizes; (void)n_in; (void)out_size; (void)ws_size;
  const float* hs = (const float*)d_in[0];
  const float* wq = (const float*)d_in[2];
  const float* wk = (const float*)d_in[3];
  const float* wv = (const float*)d_in[4];
  const float* wo = (const float*)d_in[5];
  const float* sq = (const float*)d_in[6];
  const float* sk = (const float*)d_in[7];
  const float* sv = (const float*)d_in[8];
  const float* so = (const float*)d_in[9];

  char* p = (char*)d_ws;
  const size_t MAT = (size_t)NROWS * HDIM * sizeof(u16);  // 32 MiB
  u16* Xb = (u16*)p; p += MAT;   // X bf16; later attention output
  u16* Wb = (u16*)p; p += MAT;   // weight bf16 slot (reused 4x)
  u16* Qb = (u16*)p; p += MAT;
  u16* Kb = (u16*)p; p += MAT;
  u16* Vb = (u16*)p; p += MAT;   // holds V^T (operand-swapped GEMM output)
  float* cosT = (float*)p; p += (size_t)SEQ * 64 * sizeof(float);
  float* sinT = (float*)p; p += (size_t)SEQ * 64 * sizeof(float);

  const int n4 = NROWS * (HDIM / 4);
  const dim3 cb(256);
  const int LDSZ = 131072;  // 128 KiB dynamic LDS for gemm8
  (void)hipFuncSetAttribute(reinterpret_cast<const void*>(&gemm8<0>),
                            hipFuncAttributeMaxDynamicSharedMemorySize, LDSZ);
  (void)hipFuncSetAttribute(reinterpret_cast<const void*>(&gemm8<1>),
                            hipFuncAttributeMaxDynamicSharedMemorySize, LDSZ);
  (void)hipFuncSetAttribute(reinterpret_cast<const void*>(&gemm8<2>),
                            hipFuncAttributeMaxDynamicSharedMemorySize, LDSZ);

  f2bf_vec<<<dim3(2048), cb, 0, stream>>>(hs, Xb, n4);
  rope_tables_k<<<dim3((SEQ * 64 + 255) / 256), cb, 0, stream>>>(cosT, sinT);

  f2bf_vec<<<dim3(2048), cb, 0, stream>>>(wq, Wb, n4);
  gemm8<2><<<dim3(256), dim3(512), LDSZ, stream>>>(Xb, Wb, (void*)Qb, sq, cosT, sinT);
  f2bf_vec<<<dim3(2048), cb, 0, stream>>>(wk, Wb, n4);
  gemm8<2><<<dim3(256), dim3(512), LDSZ, stream>>>(Xb, Wb, (void*)Kb, sk, cosT, sinT);
  f2bf_vec<<<dim3(2048), cb, 0, stream>>>(wv, Wb, n4);
  // operand-swapped: C[o][r] = sum_k Wv[o][k] X[r][k] = V^T  (into Vb)
  gemm8<0><<<dim3(256), dim3(512), LDSZ, stream>>>(Wb, Xb, (void*)Vb, sv, cosT, sinT);

  attn_causal<<<dim3(8, NBATCH * NHEADS), dim3(512), 0, stream>>>(Qb, Kb, Vb, Xb);

  f2bf_vec<<<dim3(2048), cb, 0, stream>>>(wo, Wb, n4);
  gemm8<1><<<dim3(256), dim3(512), LDSZ, stream>>>(Xb, Wb, d_out, so, cosT, sinT);
}

// Round 18
// 624.504 us; speedup vs baseline: 2.2300x; 1.0062x over previous
//
#include <hip/hip_runtime.h>
#include <stdint.h>
#include <math.h>

// BitNetAttention on MI355X (gfx950), round 17: intra-phase counted-lgkmcnt
// interleave in gemm8 (zero new registers). Same 12 ds_reads per phase,
// reordered bf(4) -> af[m4-groups](2 each), pinned with sched_barrier(0);
// MFMA m4-group g waits lgkmcnt(6-2g) so compute overlaps remaining reads.
// B-only phases group by n2 (lgkm 2/0). Stage/vmcnt/barrier schedule and
// register liveness identical to R16 (proven). Attn/epilogue unchanged.

#define HDIM   4096
#define SEQ    2048
#define NBATCH 2
#define NROWS  (NBATCH * SEQ)   // 4096
#define NHEADS 32
#define DHEAD  128
#define QBLK   128

typedef __attribute__((ext_vector_type(8))) short short8;
typedef __attribute__((ext_vector_type(4))) short short4v;
typedef __attribute__((ext_vector_type(4))) float f32x4;
typedef unsigned short u16;
typedef unsigned int   u32;

__device__ __forceinline__ float bf2f(u16 u) {
  union { float f; u32 i; } x; x.i = ((u32)u) << 16; return x.f;
}
__device__ __forceinline__ u16 f2bf(float f) {
  union { float f; u32 i; } x; x.f = f;
  u32 r = x.i + 0x7FFFu + ((x.i >> 16) & 1u);   // RNE
  return (u16)(r >> 16);
}
__device__ __forceinline__ u16 f2bf_t(float f) {   // truncating (cheap)
  union { float f; u32 i; } x; x.f = f;
  return (u16)(x.i >> 16);
}
// bare hardware exp2 (1 instr; FTZ + exp2(-inf)=0 fine for softmax domain)
__device__ __forceinline__ float exp2v(float x) {
  float r; asm("v_exp_f32 %0, %1" : "=v"(r) : "v"(x)); return r;
}

__device__ __forceinline__ void gload16(const u16* g, u16* l) {
  __builtin_amdgcn_global_load_lds(
      (const __attribute__((address_space(1))) u32*)g,
      (__attribute__((address_space(3))) u32*)l, 16, 0, 0);
}

__device__ __forceinline__ void unpack2(u32 v, float& a, float& b) {
  a = bf2f((u16)(v & 0xffffu)); b = bf2f((u16)(v >> 16));
}
__device__ __forceinline__ u32 pack2(float a, float b) {
  return (u32)f2bf(a) | ((u32)f2bf(b) << 16);
}

// ---------------- fp32 -> bf16 convert (vectorized) ----------------
__global__ void f2bf_vec(const float* __restrict__ in, u16* __restrict__ out, int n4) {
  int i = blockIdx.x * blockDim.x + threadIdx.x;
  const int stride = gridDim.x * blockDim.x;
  for (; i < n4; i += stride) {
    float4 v = reinterpret_cast<const float4*>(in)[i];
    u32 lo = (u32)f2bf(v.x) | ((u32)f2bf(v.y) << 16);
    u32 hi = (u32)f2bf(v.z) | ((u32)f2bf(v.w) << 16);
    reinterpret_cast<uint2*>(out)[i] = make_uint2(lo, hi);
  }
}

// ---------------- RoPE tables [SEQ][64] fp32 ----------------
__global__ void rope_tables_k(float* __restrict__ cosT, float* __restrict__ sinT) {
  int idx = blockIdx.x * blockDim.x + threadIdx.x;
  if (idx >= SEQ * 64) return;
  int s = idx >> 6, d = idx & 63;
  float ex = (float)(2 * d) / 128.0f;
  float inv = powf(10000.0f, -ex);
  float f = (float)s * inv;
  cosT[idx] = cosf(f);
  sinT[idx] = sinf(f);
}

// ---------------- 8-phase GEMM: C[4096][4096] = (A * B^T) * scale ----------------
// OUTF: 0 = bf16 out, 1 = fp32 out, 2 = bf16 out + fused RoPE (Q/K GEMMs).
template<int OUTF>
__global__ __launch_bounds__(512, 2)
void gemm8(const u16* __restrict__ Am, const u16* __restrict__ Bm,
           void* __restrict__ Cout, const float* __restrict__ scale_ptr,
           const float* __restrict__ cosT, const float* __restrict__ sinT) {
  extern __shared__ __align__(16) u16 ldsp[];

  const int tid = threadIdx.x;
  const int w = tid >> 6, lane = tid & 63;
  const int llo = lane & 15, lhi = (lane >> 4) & 3;
  const int wr = w >> 2, wc = w & 3;           // 2 x 4 waves

  const int bid = blockIdx.x;
  const int xcd = bid & 7, ii = bid >> 3;
  const int by = (xcd >> 1) * 4 + (ii & 3);
  const int bx = (xcd & 1) * 8 + (ii >> 2);
  const int rowBase = by * 256, colBase = bx * 256;
  const float scl = scale_ptr[0];

  auto stage_half = [&](const u16* G, int obase, int ts, int h, int opB) {
    const int p = ts & 1;
    const u32 base = (opB ? 32768u : 0u) + (u32)p * 16384u + (u32)h * 8192u;
#pragma unroll
    for (int i = 0; i < 2; ++i) {
      const int ru = i * 64 + w * 8;
      const int r = ru + (lane >> 3);
      const int cc = (lane & 7) ^ (r & 7);
      gload16(G + (size_t)(obase + h * 128 + r) * HDIM + ts * 64 + cc * 8,
              ldsp + base + (u32)ru * 64u);
    }
  };

  f32x4 acc[8][4];
#pragma unroll
  for (int m = 0; m < 8; ++m)
#pragma unroll
    for (int n = 0; n < 4; ++n) acc[m][n] = (f32x4)0.0f;

  // fragment registers (register-feasible set, same as R13/R16):
  short8 af_[4][2];
  short8 bf_[2][2][2];

#define SCB __builtin_amdgcn_sched_barrier(0)

#define RD_BF(NH, p_) do {                                                       \
    const u32 bb_ = (u32)(32768 + (p_) * 16384 + (NH) * 8192);                   \
    _Pragma("unroll")                                                            \
    for (int n2 = 0; n2 < 2; ++n2) { const int r_ = wc * 32 + n2 * 16 + llo;     \
      _Pragma("unroll")                                                          \
      for (int kk = 0; kk < 2; ++kk) { const int c_ = kk * 4 + lhi;              \
        bf_[NH][n2][kk] = *reinterpret_cast<const short8*>(                      \
            ldsp + bb_ + r_ * 64 + ((c_ ^ (r_ & 7)) * 8)); } }                   \
    SCB;                                                                         \
  } while (0)

#define RD_AF1(m4, MH, p_) do {                                                  \
    const u32 ab_ = (u32)((p_) * 16384 + (MH) * 8192);                           \
    const int r_ = wr * 64 + (m4) * 16 + llo;                                    \
    _Pragma("unroll")                                                            \
    for (int kk = 0; kk < 2; ++kk) { const int c_ = kk * 4 + lhi;                \
      af_[m4][kk] = *reinterpret_cast<const short8*>(                            \
          ldsp + ab_ + r_ * 64 + ((c_ ^ (r_ & 7)) * 8)); }                       \
    SCB;                                                                         \
  } while (0)

#define WAITL(n) do {                                                            \
    asm volatile("s_waitcnt lgkmcnt(" #n ")" ::: "memory");                      \
    SCB;                                                                         \
  } while (0)

#define MFMA_M4(m4, MH, NH) do {                                                 \
    _Pragma("unroll")                                                            \
    for (int n2 = 0; n2 < 2; ++n2)                                               \
      _Pragma("unroll")                                                          \
      for (int kk = 0; kk < 2; ++kk)                                             \
        acc[(MH) * 4 + (m4)][(NH) * 2 + n2] =                                    \
            __builtin_amdgcn_mfma_f32_16x16x32_bf16(                             \
                af_[m4][kk], bf_[(NH)][n2][kk],                                  \
                acc[(MH) * 4 + (m4)][(NH) * 2 + n2], 0, 0, 0);                   \
  } while (0)

#define MFMA_N2(n2, MH, NH) do {                                                 \
    _Pragma("unroll")                                                            \
    for (int m4 = 0; m4 < 4; ++m4)                                               \
      _Pragma("unroll")                                                          \
      for (int kk = 0; kk < 2; ++kk)                                             \
        acc[(MH) * 4 + m4][(NH) * 2 + (n2)] =                                    \
            __builtin_amdgcn_mfma_f32_16x16x32_bf16(                             \
                af_[m4][kk], bf_[(NH)][n2][kk],                                  \
                acc[(MH) * 4 + m4][(NH) * 2 + (n2)], 0, 0, 0);                   \
  } while (0)

#define ENDPH(VMN) do {                                                          \
    if ((VMN) == 4) asm volatile("s_waitcnt vmcnt(4)" ::: "memory");             \
    if ((VMN) == 0) asm volatile("s_waitcnt vmcnt(0)" ::: "memory");             \
    __builtin_amdgcn_s_barrier();                                                \
  } while (0)

#define STG(TS, H, OPB) stage_half((OPB) ? Bm : Am, (OPB) ? colBase : rowBase,   \
                                   (TS), (H), (OPB))

// Phase type AB (LA=1,LB=1): bf(4) + af m4-groups(2 each); waits 6/4/2/0.
#define PH_AB(TCUR, MH, NH, TS, H, OPB, DOSTAGE, VMN) do {                       \
    const int p_ = (TCUR) & 1;                                                   \
    RD_BF(NH, p_);                                                               \
    RD_AF1(0, MH, p_); RD_AF1(1, MH, p_); RD_AF1(2, MH, p_); RD_AF1(3, MH, p_);  \
    if (DOSTAGE) STG(TS, H, OPB);                                                \
    __builtin_amdgcn_s_setprio(1);                                               \
    WAITL(6); MFMA_M4(0, MH, NH);                                                \
    WAITL(4); MFMA_M4(1, MH, NH);                                                \
    WAITL(2); MFMA_M4(2, MH, NH);                                                \
    WAITL(0); MFMA_M4(3, MH, NH);                                                \
    __builtin_amdgcn_s_setprio(0);                                               \
    ENDPH(VMN);                                                                  \
  } while (0)

// Phase type B (LA=0,LB=1): bf only, n2-grouped; waits 2/0.
#define PH_B(TCUR, MH, NH, TS, H, OPB, DOSTAGE, VMN) do {                        \
    const int p_ = (TCUR) & 1;                                                   \
    const u32 bb_ = (u32)(32768 + p_ * 16384 + (NH) * 8192);                     \
    _Pragma("unroll")                                                            \
    for (int kk = 0; kk < 2; ++kk) { const int r_ = wc * 32 + llo;               \
      const int c_ = kk * 4 + lhi;                                               \
      bf_[NH][0][kk] = *reinterpret_cast<const short8*>(                         \
          ldsp + bb_ + r_ * 64 + ((c_ ^ (r_ & 7)) * 8)); }                       \
    SCB;                                                                         \
    _Pragma("unroll")                                                            \
    for (int kk = 0; kk < 2; ++kk) { const int r_ = wc * 32 + 16 + llo;          \
      const int c_ = kk * 4 + lhi;                                               \
      bf_[NH][1][kk] = *reinterpret_cast<const short8*>(                         \
          ldsp + bb_ + r_ * 64 + ((c_ ^ (r_ & 7)) * 8)); }                       \
    SCB;                                                                         \
    if (DOSTAGE) STG(TS, H, OPB);                                                \
    __builtin_amdgcn_s_setprio(1);                                               \
    WAITL(2); MFMA_N2(0, MH, NH);                                                \
    WAITL(0); MFMA_N2(1, MH, NH);                                                \
    __builtin_amdgcn_s_setprio(0);                                               \
    ENDPH(VMN);                                                                  \
  } while (0)

// Phase type A (LA=1,LB=0): af only, m4-grouped; waits 6/4/2/0.
#define PH_A(TCUR, MH, NH, TS, H, OPB, DOSTAGE, VMN) do {                        \
    const int p_ = (TCUR) & 1;                                                   \
    RD_AF1(0, MH, p_); RD_AF1(1, MH, p_); RD_AF1(2, MH, p_); RD_AF1(3, MH, p_);  \
    if (DOSTAGE) STG(TS, H, OPB);                                                \
    __builtin_amdgcn_s_setprio(1);                                               \
    WAITL(6); MFMA_M4(0, MH, NH);                                                \
    WAITL(4); MFMA_M4(1, MH, NH);                                                \
    WAITL(2); MFMA_M4(2, MH, NH);                                                \
    WAITL(0); MFMA_M4(3, MH, NH);                                                \
    __builtin_amdgcn_s_setprio(0);                                               \
    ENDPH(VMN);                                                                  \
  } while (0)

// Phase type 0 (no loads): pure MFMA.
#define PH_0(TCUR, MH, NH, TS, H, OPB, DOSTAGE, VMN) do {                        \
    if (DOSTAGE) STG(TS, H, OPB);                                                \
    __builtin_amdgcn_s_setprio(1);                                               \
    MFMA_M4(0, MH, NH); MFMA_M4(1, MH, NH);                                      \
    MFMA_M4(2, MH, NH); MFMA_M4(3, MH, NH);                                      \
    __builtin_amdgcn_s_setprio(0);                                               \
    ENDPH(VMN);                                                                  \
  } while (0)

  // prologue: T0 fully + T1 h0; vmcnt(4) -> T0 fully landed
  stage_half(Am, rowBase, 0, 0, 0);
  stage_half(Bm, colBase, 0, 0, 1);
  stage_half(Am, rowBase, 0, 1, 0);
  stage_half(Bm, colBase, 0, 1, 1);
  stage_half(Am, rowBase, 1, 0, 0);
  stage_half(Bm, colBase, 1, 0, 1);
  asm volatile("s_waitcnt vmcnt(4)" ::: "memory");
  __builtin_amdgcn_s_barrier();

  for (int it = 0; it < 31; ++it) {
    const int T = 2 * it;
    PH_AB(T,     0, 0, T + 1, 1, 0, 1, -1);
    PH_B (T,     0, 1, T + 1, 1, 1, 1, -1);
    PH_A (T,     1, 0, T + 2, 0, 0, 1, -1);
    PH_0 (T,     1, 1, T + 2, 0, 1, 1,  4);
    PH_AB(T + 1, 0, 0, T + 2, 1, 0, 1, -1);
    PH_B (T + 1, 0, 1, T + 2, 1, 1, 1, -1);
    PH_A (T + 1, 1, 0, T + 3, 0, 0, 1, -1);
    PH_0 (T + 1, 1, 1, T + 3, 0, 1, 1,  4);
  }
  PH_AB(62, 0, 0, 63, 1, 0, 1, -1);
  PH_B (62, 0, 1, 63, 1, 1, 1, -1);
  PH_A (62, 1, 0,  0, 0, 0, 0, -1);
  PH_0 (62, 1, 1,  0, 0, 0, 0,  0);
  PH_AB(63, 0, 0,  0, 0, 0, 0, -1);
  PH_B (63, 0, 1,  0, 0, 0, 0, -1);
  PH_A (63, 1, 0,  0, 0, 0, 0, -1);
  PH_0 (63, 1, 1,  0, 0, 0, 0, -1);
#undef PH_AB
#undef PH_B
#undef PH_A
#undef PH_0
#undef RD_BF
#undef RD_AF1
#undef WAITL
#undef MFMA_M4
#undef MFMA_N2
#undef ENDPH
#undef STG
#undef SCB

  // ---- epilogue: LDS-bounced coalesced stores
  if (OUTF == 1) {
    float* ldf = reinterpret_cast<float*>(ldsp);
    float* Cf = reinterpret_cast<float*>(Cout);
#pragma unroll
    for (int hh = 0; hh < 2; ++hh) {
      if (hh) __syncthreads();
#pragma unroll
      for (int mf2 = 0; mf2 < 4; ++mf2)
#pragma unroll
        for (int nf = 0; nf < 4; ++nf)
#pragma unroll
          for (int r = 0; r < 4; ++r) {
            const int mf = hh * 4 + mf2;
            const int rowL = wr * 64 + mf2 * 16 + lhi * 4 + r;       // 0..127
            const int col = (nf >> 1) * 128 + wc * 32 + (nf & 1) * 16 + llo;
            ldf[rowL * 256 + col] = acc[mf][nf][r] * scl;
          }
      __syncthreads();
#pragma unroll
      for (int k = 0; k < 16; ++k) {
        const int rowL = k * 8 + w;
        const float4 v = *reinterpret_cast<const float4*>(&ldf[rowL * 256 + lane * 4]);
        *reinterpret_cast<float4*>(
            &Cf[(size_t)(rowBase + hh * 128 + rowL) * HDIM + colBase + lane * 4]) = v;
      }
    }
  } else {
#pragma unroll
    for (int mf = 0; mf < 8; ++mf)
#pragma unroll
      for (int nf = 0; nf < 4; ++nf)
#pragma unroll
        for (int r = 0; r < 4; ++r) {
          const int row = (mf >> 2) * 128 + wr * 64 + (mf & 3) * 16 + lhi * 4 + r;
          const int col = (nf >> 1) * 128 + wc * 32 + (nf & 1) * 16 + llo;
          ldsp[row * 256 + col] = f2bf(acc[mf][nf][r] * scl);
        }
    __syncthreads();
    u16* Cb = reinterpret_cast<u16*>(Cout);
#pragma unroll
    for (int k = 0; k < 16; ++k) {
      const int row = k * 16 + w * 2 + (lane >> 5);   // 2 rows/wave, contig 1 KiB
      const int ch = lane & 31;
      if (OUTF == 2) {
        // fused RoPE: pair (d, d+64) within head = col ^ 64 (bit6; head bit7)
        const int R = rowBase + row;
        const int pos = R & (SEQ - 1);
        const int cb = ch * 8;
        const int dl = cb & 63;
        const bool lohalf = (cb & 64) == 0;
        const short8 xv = *reinterpret_cast<const short8*>(&ldsp[row * 256 + cb]);
        const short8 pv = *reinterpret_cast<const short8*>(&ldsp[row * 256 + (cb ^ 64)]);
        const float* cT = &cosT[pos * 64 + dl];
        const float* sT = &sinT[pos * 64 + dl];
        u32 wds[4];
#pragma unroll
        for (int jj = 0; jj < 4; ++jj) {
          const float c0 = cT[jj * 2], c1 = cT[jj * 2 + 1];
          const float s0 = sT[jj * 2], s1 = sT[jj * 2 + 1];
          const float x0 = bf2f((u16)xv[jj * 2]), x1 = bf2f((u16)xv[jj * 2 + 1]);
          const float p0 = bf2f((u16)pv[jj * 2]), p1 = bf2f((u16)pv[jj * 2 + 1]);
          const float o0 = lohalf ? (x0 * c0 - p0 * s0) : (x0 * c0 + p0 * s0);
          const float o1 = lohalf ? (x1 * c1 - p1 * s1) : (x1 * c1 + p1 * s1);
          wds[jj] = pack2(o0, o1);
        }
        uint4 ov = make_uint4(wds[0], wds[1], wds[2], wds[3]);
        *reinterpret_cast<uint4*>(&Cb[(size_t)R * HDIM + colBase + cb]) = ov;
      } else {
        const short8 v = *reinterpret_cast<const short8*>(&ldsp[row * 256 + ch * 8]);
        *reinterpret_cast<short8*>(&Cb[(size_t)(rowBase + row) * HDIM + colBase + ch * 8]) = v;
      }
    }
  }
}

// ---------------- flash-causal attention ----------------
// Grid (8, 64); block x does q-tiles x and 15-x (triangle fold, equal work).
// KVBLK=64. K/V via XOR-source-swizzled global_load_lds; counted vmcnt(2)
// keeps K(t+1) in flight over the mid-tile publish barrier.
// Swapped QK^T: lane owns q-row llo; in-lane softmax + 2 shfl_xor.
__global__ __launch_bounds__(512, 4)
void attn_causal(const u16* __restrict__ Q, const u16* __restrict__ K,
                 const u16* __restrict__ VT, u16* __restrict__ O) {
  __shared__ __align__(16) u16 Ks[2][64][128];
  __shared__ __align__(16) u16 Vt[128][64];
  __shared__ __align__(16) u16 Pw[8][16][76];

  const int tid = threadIdx.x;
  const int w = tid >> 6, lane = tid & 63;
  const int lhi = lane >> 4, llo = lane & 15;
  const int bh = blockIdx.y, b = bh >> 5, h = bh & 31;

  const u16* Kg = K + ((size_t)b * SEQ) * HDIM + h * DHEAD;
  const u16* VTg = VT + (size_t)(h * DHEAD) * NROWS + b * SEQ;   // [d][s], stride NROWS

  const int kcp = tid & 15;                 // K staging chunk (16 per row)
  const int vrl = tid >> 3, vcp = tid & 7;  // V staging: row-low, chunk (8 per row)

  const float smul2 = 0.127517427f;         // (1/sqrt(128)) * log2(e)

  for (int halfq = 0; halfq < 2; ++halfq) {
    const int xq = (halfq == 0) ? (int)blockIdx.x : 15 - (int)blockIdx.x;
    const int qb = xq * QBLK;
    const int ntile = qb / 64 + 2;
    const int wmax = qb + w * 16 + 15;
    const int qrow = qb + w * 16 + llo;     // lane-owned q-row (swapped layout)

    const u16* Qg = Q + ((size_t)(b * SEQ + qb)) * HDIM + h * DHEAD;
    short8 qf[4];
#pragma unroll
    for (int dc = 0; dc < 4; ++dc)
      qf[dc] = *reinterpret_cast<const short8*>(Qg + (size_t)(w * 16 + llo) * HDIM + dc * 32 + lhi * 8);

    f32x4 o[8];
#pragma unroll
    for (int dt = 0; dt < 8; ++dt) o[dt] = (f32x4)0.0f;
    float mrow = -__builtin_inff(), lrow = 0.0f;

    // prologue: K(0) -> Ks[0]
    {
      u16* dst = &Ks[0][0][0] + tid * 8;
#pragma unroll
      for (int i = 0; i < 2; ++i) {
        const int r = i * 32 + (tid >> 4);
        const int cs = kcp ^ (r & 7);
        gload16(Kg + (size_t)r * HDIM + cs * 8, dst + i * 4096);
      }
    }
    __syncthreads();
    int buf = 0;

    for (int t = 0; t < ntile; ++t) {
      const int kv0 = t * 64;
      // issue V(t) -> Vt (single buffer; readers of V(t-1) joined at tile end)
      {
        u16* dst = &Vt[0][0] + tid * 8;
#pragma unroll
        for (int i = 0; i < 2; ++i) {
          const int rV = i * 64 + vrl;
          const int cs = vcp ^ (rV & 7);
          gload16(VTg + (size_t)rV * NROWS + kv0 + cs * 8, dst + i * 4096);
        }
      }
      const bool haveK = (t + 1 < ntile);
      if (haveK) {
        u16* dst = &Ks[buf ^ 1][0][0] + tid * 8;
        const int nkv = kv0 + 64;
#pragma unroll
        for (int i = 0; i < 2; ++i) {
          const int r = i * 32 + (tid >> 4);
          const int cs = kcp ^ (r & 7);
          gload16(Kg + (size_t)(nkv + r) * HDIM + cs * 8, dst + i * 4096);
        }
      }

      const bool docomp = (kv0 <= wmax);
      union { short4v hh[2]; short8 v8; } pu[2];
      if (docomp) {
        f32x4 sacc[4];
#pragma unroll
        for (int nt2 = 0; nt2 < 4; ++nt2) sacc[nt2] = (f32x4)0.0f;
        __builtin_amdgcn_s_setprio(1);
#pragma unroll
        for (int nt2 = 0; nt2 < 4; ++nt2) {
          const int r = nt2 * 16 + llo;
#pragma unroll
          for (int dc = 0; dc < 4; ++dc) {
            const int cs = (dc * 4 + lhi) ^ (r & 7);
            const short8 kf = *reinterpret_cast<const short8*>(&Ks[buf][r][cs * 8]);
            // SWAPPED: A=K (row=llo -> kcol), B=Q (col=llo -> qrow)
            sacc[nt2] = __builtin_amdgcn_mfma_f32_16x16x32_bf16(kf, qf[dc], sacc[nt2], 0, 0, 0);
          }
        }
        __builtin_amdgcn_s_setprio(0);

        // lane holds S[qrow][kcol = kv0 + nt2*16 + lhi*4 + i]
        const int thr = qrow - kv0 - lhi * 4;   // mask: nt2*16 + i <= thr
        float sv[4][4];
#pragma unroll
        for (int nt2 = 0; nt2 < 4; ++nt2)
#pragma unroll
          for (int i = 0; i < 4; ++i) {
            const float xv = sacc[nt2][i] * smul2;
            sv[nt2][i] = (nt2 * 16 + i <= thr) ? xv : -__builtin_inff();
          }

        // in-lane max over 16, then combine across the 4 lhi-lanes (same llo)
        float rmax = sv[0][0];
#pragma unroll
        for (int nt2 = 0; nt2 < 4; ++nt2)
#pragma unroll
          for (int i = 0; i < 4; ++i) rmax = fmaxf(rmax, sv[nt2][i]);
        rmax = fmaxf(rmax, __shfl_xor(rmax, 16));
        rmax = fmaxf(rmax, __shfl_xor(rmax, 32));

        // narrow defer-max: only the rescale is guarded
        const bool need = (rmax > mrow + 8.0f);
        if (__any((int)need)) {
          const float mn = fmaxf(mrow, rmax);
          const float facl = exp2v(mrow - mn);
          mrow = mn;
          lrow *= facl;
          float facr[4];
#pragma unroll
          for (int r = 0; r < 4; ++r) facr[r] = __shfl(facl, lhi * 4 + r);
#pragma unroll
          for (int dt = 0; dt < 8; ++dt)
#pragma unroll
            for (int r = 0; r < 4; ++r) o[dt][r] *= facr[r];
        }

        float p[4][4];
        float rsum = 0.0f;
#pragma unroll
        for (int nt2 = 0; nt2 < 4; ++nt2)
#pragma unroll
          for (int i = 0; i < 4; ++i) {
            p[nt2][i] = exp2v(sv[nt2][i] - mrow);
            rsum += p[nt2][i];
          }
        rsum += __shfl_xor(rsum, 16);
        rsum += __shfl_xor(rsum, 32);
        lrow += rsum;

        // P -> Pw[qrow=llo][kcol]; each lane writes its 16 owned kcols
#pragma unroll
        for (int nt2 = 0; nt2 < 4; ++nt2)
#pragma unroll
          for (int i = 0; i < 4; ++i)
            Pw[w][llo][nt2 * 16 + lhi * 4 + i] = f2bf_t(p[nt2][i]);

#pragma unroll
        for (int s = 0; s < 2; ++s) {
          pu[s].hh[0] = *reinterpret_cast<const short4v*>(&Pw[w][llo][s * 32 + lhi * 8]);
          pu[s].hh[1] = *reinterpret_cast<const short4v*>(&Pw[w][llo][s * 32 + lhi * 8 + 4]);
        }
      }

      // publish V(t): each wave waits its own V loads (2 oldest), then joins.
      if (haveK) asm volatile("s_waitcnt vmcnt(2)" ::: "memory");
      else       asm volatile("s_waitcnt vmcnt(0)" ::: "memory");
      __builtin_amdgcn_s_barrier();

      if (docomp) {
        __builtin_amdgcn_s_setprio(1);
#pragma unroll
        for (int dt = 0; dt < 8; ++dt)
#pragma unroll
          for (int s = 0; s < 2; ++s) {
            const int rr = dt * 16 + llo;
            const int cs = (s * 4 + lhi) ^ (rr & 7);
            const short8 vf = *reinterpret_cast<const short8*>(&Vt[rr][cs * 8]);
            o[dt] = __builtin_amdgcn_mfma_f32_16x16x32_bf16(pu[s].v8, vf, o[dt], 0, 0, 0);
          }
        __builtin_amdgcn_s_setprio(0);
      }
      __syncthreads();   // joins waves; drains K(t+1) (issued a full tile ago)
      buf ^= 1;
    }

    u16* Og = O + ((size_t)(b * SEQ + qb)) * HDIM + h * DHEAD;
    float invr[4];
#pragma unroll
    for (int r = 0; r < 4; ++r) invr[r] = 1.0f / __shfl(lrow, lhi * 4 + r);
#pragma unroll
    for (int dt = 0; dt < 8; ++dt)
#pragma unroll
      for (int r = 0; r < 4; ++r)
        Og[(size_t)(w * 16 + lhi * 4 + r) * HDIM + dt * 16 + llo] = f2bf(o[dt][r] * invr[r]);
  }
}

// ---------------- launch ----------------
extern "C" void kernel_launch(void* const* d_in, const int* in_sizes, int n_in,
                              void* d_out, int out_size, void* d_ws, size_t ws_size,
                              hipStream_t stream) {
  (void)in_sizes; (void)n_in; (void)out_size; (void)ws_size;
  const float* hs = (const float*)d_in[0];
  const float* wq = (const float*)d_in[2];
  const float* wk = (const float*)d_in[3];
  const float* wv = (const float*)d_in[4];
  const float* wo = (const float*)d_in[5];
  const float* sq = (const float*)d_in[6];
  const float* sk = (const float*)d_in[7];
  const float* sv = (const float*)d_in[8];
  const float* so = (const float*)d_in[9];

  char* p = (char*)d_ws;
  const size_t MAT = (size_t)NROWS * HDIM * sizeof(u16);  // 32 MiB
  u16* Xb = (u16*)p; p += MAT;   // X bf16; later attention output
  u16* Wb = (u16*)p; p += MAT;   // weight bf16 slot (reused 4x)
  u16* Qb = (u16*)p; p += MAT;
  u16* Kb = (u16*)p; p += MAT;
  u16* Vb = (u16*)p; p += MAT;   // holds V^T (operand-swapped GEMM output)
  float* cosT = (float*)p; p += (size_t)SEQ * 64 * sizeof(float);
  float* sinT = (float*)p; p += (size_t)SEQ * 64 * sizeof(float);

  const int n4 = NROWS * (HDIM / 4);
  const dim3 cb(256);
  const int LDSZ = 131072;  // 128 KiB dynamic LDS for gemm8
  (void)hipFuncSetAttribute(reinterpret_cast<const void*>(&gemm8<0>),
                            hipFuncAttributeMaxDynamicSharedMemorySize, LDSZ);
  (void)hipFuncSetAttribute(reinterpret_cast<const void*>(&gemm8<1>),
                            hipFuncAttributeMaxDynamicSharedMemorySize, LDSZ);
  (void)hipFuncSetAttribute(reinterpret_cast<const void*>(&gemm8<2>),
                            hipFuncAttributeMaxDynamicSharedMemorySize, LDSZ);

  f2bf_vec<<<dim3(2048), cb, 0, stream>>>(hs, Xb, n4);
  rope_tables_k<<<dim3((SEQ * 64 + 255) / 256), cb, 0, stream>>>(cosT, sinT);

  f2bf_vec<<<dim3(2048), cb, 0, stream>>>(wq, Wb, n4);
  gemm8<2><<<dim3(256), dim3(512), LDSZ, stream>>>(Xb, Wb, (void*)Qb, sq, cosT, sinT);
  f2bf_vec<<<dim3(2048), cb, 0, stream>>>(wk, Wb, n4);
  gemm8<2><<<dim3(256), dim3(512), LDSZ, stream>>>(Xb, Wb, (void*)Kb, sk, cosT, sinT);
  f2bf_vec<<<dim3(2048), cb, 0, stream>>>(wv, Wb, n4);
  // operand-swapped: C[o][r] = sum_k Wv[o][k] X[r][k] = V^T  (into Vb)
  gemm8<0><<<dim3(256), dim3(512), LDSZ, stream>>>(Wb, Xb, (void*)Vb, sv, cosT, sinT);

  attn_causal<<<dim3(8, NBATCH * NHEADS), dim3(512), 0, stream>>>(Qb, Kb, Vb, Xb);

  f2bf_vec<<<dim3(2048), cb, 0, stream>>>(wo, Wb, n4);
  gemm8<1><<<dim3(256), dim3(512), LDSZ, stream>>>(Xb, Wb, d_out, so, cosT, sinT);
}